// Round 8
// baseline (160.969 us; speedup 1.0000x reference)
//
#include <hip/hip_runtime.h>
#include <hip/hip_bf16.h>

// Problem constants
#define B_   16
#define C_   256
#define T_   2048
#define PS   12
#define NNEG 15
#define OFFS 16
#define COPIES 16

// Derived
#define M_GEMM (B_ * T_)        // 32768 rows (b,t)
#define N_GEMM (C_ * PS)        // 3072
#define NPRED 6225408           // sum_i (2032-i)*256
#define NLAB  389088

using bf16 = __hip_bfloat16;
typedef __attribute__((ext_vector_type(4))) float f32x4;
typedef __attribute__((ext_vector_type(8))) short bf16x8;

#define WAITVM(n) asm volatile("s_waitcnt vmcnt(" #n ")" ::: "memory")
#define GLL(src, dst)                                                        \
    __builtin_amdgcn_global_load_lds(                                        \
        (const __attribute__((address_space(1))) void*)(src),                \
        (__attribute__((address_space(3))) void*)(dst), 16, 0, 0)

// ---------------------------------------------------------------- transpose z
// z[b][c][t] f32  ->  zT[b][t][c] bf16
__global__ __launch_bounds__(256) void transpose_z(const float* __restrict__ z,
                                                   bf16* __restrict__ zT) {
    __shared__ float tile[32][33];
    int t0 = blockIdx.x * 32, c0 = blockIdx.y * 32, b = blockIdx.z;
    int col = threadIdx.x & 31, r = threadIdx.x >> 5;
    for (int rr = 0; rr < 4; ++rr) {
        int row = r + rr * 8;
        tile[row][col] = z[(size_t)(b * C_ + c0 + row) * T_ + t0 + col];
    }
    __syncthreads();
    for (int rr = 0; rr < 4; ++rr) {
        int row = r + rr * 8;
        zT[(size_t)(b * T_ + t0 + row) * C_ + c0 + col] =
            __float2bfloat16(tile[col][row]);
    }
}

// ---------------------------------------------------------------- pack weight
// w[c][o][i] f32 -> wTb[j][c] bf16 with j = i*256 + o
__global__ __launch_bounds__(256) void pack_w(const float* __restrict__ w,
                                              bf16* __restrict__ wTb) {
    int gid = blockIdx.x * 256 + threadIdx.x;
    int j = gid >> 8, c = gid & 255;
    int o = j & 255, i = j >> 8;
    wTb[gid] = __float2bfloat16(w[(size_t)c * (C_ * PS) + o * PS + i]);
}

// ---------------------------------------------------------------- z_pred GEMM
// Round 8: BM=64 x BN=256 (one i, full c-range per block), 4 waves (1x4),
// BK=32, 2-slot ping-pong (20KB/slot) with counted WAITVM(5).
// zp layout now i-major: zp[i][b][s][c] -> each block's store is ONE
// contiguous 32KB stream (64 consecutive s x 512B full rows).
#define EPAD 264   // epilogue row stride (elements)

__global__ __launch_bounds__(256) void gemm_zpred(const bf16* __restrict__ zT,
                                                  const bf16* __restrict__ wTb,
                                                  const float* __restrict__ bias,
                                                  bf16* __restrict__ zp) {
    __shared__ __align__(16) char smem[40960];   // 2 x 20480 (lA 4KB + lB 16KB)
    bf16* lE = (bf16*)smem;

    // bijective XCD swizzle: grid = 6144 = 8 * 768
    int bid = (blockIdx.x & 7) * 768 + (blockIdx.x >> 3);
    int i_step = bid % PS;          // 0..11
    int bm = bid / PS;              // 0..511
    int tid = threadIdx.x;
    int wid = tid >> 6, lane = tid & 63;
    int ln15 = lane & 15, kg = lane >> 4;
    int wn = wid * 64;              // wave's n-range (c-channels)
    int row0 = bm * 64;             // global (b,t) row; 64-row tile: no b straddle
    int b = row0 >> 11, t0 = row0 & (T_ - 1);

    // staging source (pre-swizzled granule: g' = g ^ ((row>>1)&3))
    int gsw = ((lane & 3) ^ ((lane >> 3) & 3)) * 8;
    const bf16* srcA = zT + (size_t)(row0 + wid * 16 + (lane >> 2)) * 256 + gsw;
    const bf16* srcB =
        wTb + (size_t)(i_step * 256 + wid * 64 + (lane >> 2)) * 256 + gsw;

    // fragment LDS byte offsets within a slot (lA @0 [64][32], lB @4096 [256][32])
    int offA[4], offB[4];
#pragma unroll
    for (int mi = 0; mi < 4; ++mi) {
        int r = mi * 16 + ln15;
        offA[mi] = r * 64 + ((kg ^ ((r >> 1) & 3)) * 16);
    }
#pragma unroll
    for (int ni = 0; ni < 4; ++ni) {
        int c = wn + ni * 16 + ln15;
        offB[ni] = 4096 + c * 64 + ((kg ^ ((c >> 1) & 3)) * 16);
    }

    f32x4 acc[4][4] = {};

    // per-wave per-stage: 1 A-GLL + 4 B-GLL = 5 outstanding units
#define STAGE(t, slot_base)                                                  \
    {                                                                        \
        char* d = smem + (slot_base);                                        \
        const bf16* sa = srcA + (t) * 32;                                    \
        const bf16* sbw = srcB + (t) * 32;                                   \
        GLL(sa, d + wid * 1024);                                             \
        GLL(sbw, d + 4096 + wid * 4096);                                     \
        GLL(sbw + 16 * 256, d + 4096 + wid * 4096 + 1024);                   \
        GLL(sbw + 32 * 256, d + 4096 + wid * 4096 + 2048);                   \
        GLL(sbw + 48 * 256, d + 4096 + wid * 4096 + 3072);                   \
    }

    // frags secured in regs (lgkmcnt(0)+sched_barrier+barrier), THEN restage
    // the same slot for t+2 (counted vmcnt keeps next stage in flight).
#define TILE_BODY(slot_base, VMN, PREF)                                      \
    {                                                                        \
        WAITVM(VMN);                                                         \
        __builtin_amdgcn_s_barrier();                                        \
        const char* sb = smem + (slot_base);                                 \
        bf16x8 af[4], bfr[4];                                                \
        _Pragma("unroll") for (int mi = 0; mi < 4; ++mi)                     \
            af[mi] = *(const bf16x8*)(sb + offA[mi]);                        \
        _Pragma("unroll") for (int ni = 0; ni < 4; ++ni)                     \
            bfr[ni] = *(const bf16x8*)(sb + offB[ni]);                       \
        asm volatile("s_waitcnt lgkmcnt(0)" ::: "memory");                   \
        __builtin_amdgcn_sched_barrier(0);                                   \
        __builtin_amdgcn_s_barrier();                                        \
        PREF;                                                                \
        __builtin_amdgcn_s_setprio(1);                                       \
        _Pragma("unroll") for (int mi = 0; mi < 4; ++mi)                     \
            _Pragma("unroll") for (int ni = 0; ni < 4; ++ni)                 \
                acc[mi][ni] = __builtin_amdgcn_mfma_f32_16x16x32_bf16(       \
                    af[mi], bfr[ni], acc[mi][ni], 0, 0, 0);                  \
        __builtin_amdgcn_s_setprio(0);                                       \
    }

    STAGE(0, 0);
    STAGE(1, 20480);
    TILE_BODY(0,     5, STAGE(2, 0));        // k-tile 0
    TILE_BODY(20480, 5, STAGE(3, 20480));    // k-tile 1
    TILE_BODY(0,     5, STAGE(4, 0));
    TILE_BODY(20480, 5, STAGE(5, 20480));
    TILE_BODY(0,     5, STAGE(6, 0));
    TILE_BODY(20480, 5, STAGE(7, 20480));
    TILE_BODY(0,     5, );                   // k-tile 6 (stage7 in flight)
    TILE_BODY(20480, 0, );                   // k-tile 7 (drain)

    // ---------------- epilogue: acc -> LDS bf16 (+bias) -> contiguous stores
    __syncthreads();

    float bv[4];
#pragma unroll
    for (int ni = 0; ni < 4; ++ni) bv[ni] = bias[wn + ni * 16 + ln15];

#pragma unroll
    for (int mi = 0; mi < 4; ++mi)
#pragma unroll
        for (int ni = 0; ni < 4; ++ni) {
            int col_e = wn + ni * 16 + ln15;
#pragma unroll
            for (int r = 0; r < 4; ++r) {
                int row_e = mi * 16 + kg * 4 + r;
                lE[row_e * EPAD + col_e] = __float2bfloat16(acc[mi][ni][r] + bv[ni]);
            }
        }

    __syncthreads();

    // zp[i][b][s][c]: rows s = t0+16+i .. contiguous; 512B per row
    size_t zbase = ((size_t)(i_step * B_ + b) * T_ + (t0 + OFFS + i_step)) * 256;
#pragma unroll
    for (int e = 0; e < 8; ++e) {
        int row_e = e * 8 + (tid >> 5);
        if (t0 + row_e + OFFS + i_step < T_) {
            bf16x8 v = *(const bf16x8*)&lE[row_e * EPAD + (tid & 31) * 8];
            *(bf16x8*)(zp + zbase + (size_t)row_e * 256 + (tid & 31) * 8) = v;
        }
    }
#undef STAGE
#undef TILE_BODY
}

// ---------------------------------------------------------------- predictions
// Structure unchanged from round 7; zp addressing updated to i-major layout.
__global__ __launch_bounds__(256) void predict_kernel(
    const bf16* __restrict__ zT, const bf16* __restrict__ zp,
    const int* __restrict__ neg, float* __restrict__ out) {
    __shared__ __align__(16) char psm[131072];
    int tid = threadIdx.x;
    int wid = tid >> 6, lane = tid & 63;
    int ln15 = lane & 15, kg = lane >> 4;
    char* my = psm + wid * 32768;           // wave-private: 2 slots x 16KB
    int base_gi = (blockIdx.x * 4 + wid) * 8;
    int b = base_gi / (T_ - OFFS);          // 8 | 2032: whole wave shares b
    int s_base = OFFS + base_gi % (T_ - OFFS);

    const char* zTb = (const char*)zT;
    const char* zpb = (const char*)zp;

    // prologue: preload all neg rows for the wave's 8 (b,s) pairs
    int srcrow[8];
    if (lane == 0) {
#pragma unroll
        for (int it = 0; it < 8; ++it) srcrow[it] = b * T_ + s_base + it;
    } else if (lane < 16) {
        const int* np = neg + b * (NNEG * T_) + (lane - 1) * T_ + s_base;
        int4 n0 = *(const int4*)np;
        int4 n1 = *(const int4*)(np + 4);
        srcrow[0] = n0.x; srcrow[1] = n0.y; srcrow[2] = n0.z; srcrow[3] = n0.w;
        srcrow[4] = n1.x; srcrow[5] = n1.y; srcrow[6] = n1.z; srcrow[7] = n1.w;
    } else {
#pragma unroll
        for (int it = 0; it < 8; ++it) srcrow[it] = 0;
    }

    auto stage = [&](int it, int slot, int sr) {
        int s = s_base + it;
        char* dst = my + slot * 16384;
        int half = lane >> 5;
        int g31 = lane & 31;
#pragma unroll
        for (int j = 0; j < 8; ++j) {
            int r0 = __shfl(sr, 2 * j);
            int r1 = __shfl(sr, 2 * j + 1);
            int row = half ? r1 : r0;
            int n = 2 * j + half;
            GLL(zTb + (size_t)row * 512 + ((g31 ^ (n & 7)) << 4),
                dst + j * 1024);
        }
#pragma unroll
        for (int j = 0; j < 6; ++j) {
            int i0 = 2 * j + half;          // zp row (step i) 0..11
            GLL(zpb + ((size_t)(i0 * B_ + b) * T_ + s) * 512 +
                    ((g31 ^ (i0 & 7)) << 4),
                dst + 8192 + j * 1024);
        }
    };

    auto compute = [&](int it, int slot) {
        const char* sb = my + slot * 16384;
        int ii = ln15 < 12 ? ln15 : 0;      // dup col 0 for pad lanes (bcast)
        bf16x8 af[8], bfr[8];
#pragma unroll
        for (int kk = 0; kk < 8; ++kk) {
            int g = kk * 4 + kg;
            af[kk] = *(const bf16x8*)(sb + ln15 * 512 + ((g ^ (ln15 & 7)) << 4));
            bfr[kk] = *(const bf16x8*)(sb + 8192 + ii * 512 + ((g ^ (ii & 7)) << 4));
        }
        asm volatile("s_waitcnt lgkmcnt(0)" ::: "memory");
        __builtin_amdgcn_sched_barrier(0);
        if (it + 2 < 8) stage(it + 2, slot, srcrow[it + 2 < 8 ? it + 2 : 0]);

        f32x4 acc = {0.f, 0.f, 0.f, 0.f};
#pragma unroll
        for (int kk = 0; kk < 8; ++kk)
            acc = __builtin_amdgcn_mfma_f32_16x16x32_bf16(af[kk], bfr[kk], acc,
                                                          0, 0, 0);

        int s = s_base + it;
        int i = ln15;
        int imax = s - OFFS; if (imax > PS - 1) imax = PS - 1;
        if (i <= imax) {
            int t = s - OFFS - i;
            int base_i = 256 * ((T_ - OFFS) * i - (i * (i - 1)) / 2);
            float* o = out + base_i + (t * B_ + b) * COPIES + kg * 4;
            *(f32x4*)o = acc;               // single 16B store
        }
    };

    stage(0, 0, srcrow[0]);
    stage(1, 1, srcrow[1]);

    WAITVM(14); compute(0, 0);
    WAITVM(15); compute(1, 1);
    WAITVM(15); compute(2, 0);
    WAITVM(15); compute(3, 1);
    WAITVM(15); compute(4, 0);
    WAITVM(15); compute(5, 1);
    WAITVM(15); compute(6, 0);
    WAITVM(1);  compute(7, 1);
}

// ---------------------------------------------------------------- launch
extern "C" void kernel_launch(void* const* d_in, const int* in_sizes, int n_in,
                              void* d_out, int out_size, void* d_ws, size_t ws_size,
                              hipStream_t stream) {
    const float* z    = (const float*)d_in[0];
    const float* w    = (const float*)d_in[1];
    const float* bias = (const float*)d_in[2];
    const int*   neg  = (const int*)d_in[3];
    float* out = (float*)d_out;

    char* ws = (char*)d_ws;
    const size_t ZP_BYTES = (size_t)PS * B_ * T_ * 256 * sizeof(bf16);  // i-major
    bf16* zp  = (bf16*)ws;
    bf16* zT  = (bf16*)(ws + ZP_BYTES + 8192);
    bf16* wTb = (bf16*)(ws + ZP_BYTES + 8192 + (size_t)M_GEMM * 256 * sizeof(bf16));

    transpose_z<<<dim3(T_ / 32, C_ / 32, B_), 256, 0, stream>>>(z, zT);
    pack_w<<<(N_GEMM * 256) / 256, 256, 0, stream>>>(w, wTb);
    gemm_zpred<<<(M_GEMM / 64) * PS, 256, 0, stream>>>(zT, wTb, bias, zp);
    predict_kernel<<<(B_ * (T_ - OFFS)) / 32, 256, 0, stream>>>(zT, zp, neg, out);
    hipMemsetAsync(out + NPRED, 0, NLAB * sizeof(float), stream);
}